// Round 31
// baseline (105.962 us; speedup 1.0000x reference)
//
#include <hip/hip_runtime.h>
#include <stdint.h>

#define SEQ_LEN 120
#define N_JOINTS 25
#define NTOK 3000
#define D 512
#define NH 8
#define DH 64
#define BS 2
#define ROWS (BS*NTOK)       // 6000
#define EPS_ATT 1e-6f
#define EPS_LN 1e-6f

typedef unsigned short u16;
typedef __attribute__((ext_vector_type(8))) short short8_t;
typedef __attribute__((ext_vector_type(4))) short short4_t;
typedef __attribute__((ext_vector_type(4))) float f32x4;

// ws layout (bytes); ws_size = 288 MB confirmed
#define OFF_WT   ((size_t)65536)                      // 4*512*512*2 bf16
#define OFF_QKV  ((size_t)(OFF_WT + 2097152))         // 3*6000*512*2 bf16
#define OFF_HATT ((size_t)(OFF_QKV + 36864000))       // 6000*512*2 bf16 (H, then attnout)
#define OFF_M    ((size_t)(OFF_HATT + 6144000))       // 48000*4
#define OFF_L    ((size_t)(OFF_M + 192000))           // 48000*4
#define OFF_CNT  ((size_t)(OFF_L + 192000))           // 6000*4
#define WS_NEEDED (OFF_CNT + 24064)

#define GEMM_BLKS (24*47)    // 1128 gemm tiles
#define ZROWS_PER_BLK 4      // zscan rows per block
#define ZS_BLKS (ROWS / ZROWS_PER_BLK)   // 1500 zscan blocks, dispatched FIRST

__device__ inline u16 f2bf(float f) {
    union { float f; uint32_t u; } c; c.f = f;
    uint32_t u = c.u;
    u += 0x7FFFu + ((u >> 16) & 1u);   // RNE
    return (u16)(u >> 16);
}
__device__ inline float bf2f(u16 h) {
    union { uint32_t u; float f; } c; c.u = ((uint32_t)h) << 16;
    return c.f;
}

__global__ void sentinel_kernel(float* __restrict__ out, int n, float v) {
    int i = blockIdx.x * 256 + threadIdx.x;
    if (i < n) out[i] = v;
}

// ---- prep: addpe [0,1500) | transW [1500,2524) ----------------------------
__global__ __launch_bounds__(256)
void prep_kernel(const float* __restrict__ x,
                 const float* __restrict__ Wq, const float* __restrict__ Wk,
                 const float* __restrict__ Wv, const float* __restrict__ Wo,
                 u16* __restrict__ Hb, u16* __restrict__ WT) {
    int bid = blockIdx.x;
    int t = threadIdx.x;
    __shared__ float tile[32][33];

    if (bid < 1500) {
        // ---- addpe: Hb = bf16(x + pe), PE computed inline
        int idx = (bid * 256 + t) * 8;
        int r = idx >> 9, c = idx & 511;
        int p = (r % NTOK) % N_JOINTS;
        const float* xr = x + idx;
        short8_t o;
        #pragma unroll
        for (int e = 0; e < 8; e++) {
            int cc = c + e;
            float dt = expf((float)(cc & ~1) * (-9.210340371976184f / 512.0f));
            float arg = (float)p * dt;
            float pev = (cc & 1) ? cosf(arg) : sinf(arg);
            o[e] = (short)f2bf(xr[e] + pev);
        }
        *(short8_t*)(Hb + idx) = o;
    } else {
        // ---- transW: WT[w][n][k] = bf16(W[w][k][n])
        int idx2 = bid - 1500;              // 0..1023
        int w = idx2 >> 8;
        int rem = idx2 & 255;
        int n0 = (rem & 15) * 32;
        int k0 = (rem >> 4) * 32;
        const float* W = (w == 0) ? Wq : (w == 1) ? Wk : (w == 2) ? Wv : Wo;
        int tx = t & 31, ty2 = t >> 5;      // ty2 0..7
        #pragma unroll
        for (int e = 0; e < 4; e++) {
            int row = ty2 + e * 8;
            tile[row][tx] = W[(size_t)(k0 + row) * D + n0 + tx];
        }
        __syncthreads();
        #pragma unroll
        for (int e = 0; e < 4; e++) {
            int row = ty2 + e * 8;
            WT[(size_t)w * D * D + (size_t)(n0 + row) * D + k0 + tx] = f2bf(tile[tx][row]);
        }
    }
}

// ---- fused zscan (FIRST, saturates HBM) + QKV GEMM (BM=128, BK=64) --------
// blocks [0,1500): zscan, 4 adj rows each — short-lived, stream at full BW;
// blocks [1500,2628): gemm tiles — MFMA overlaps remaining adj streaming.
__global__ __launch_bounds__(256)
void gemm_qkv(const u16* __restrict__ Hb, const u16* __restrict__ WT,
              const float* __restrict__ bq, const float* __restrict__ bk,
              const float* __restrict__ bvb, u16* __restrict__ qkv,
              const float* __restrict__ adj, int* __restrict__ cnt0) {
    __shared__ __align__(16) u16 As[128][72];   // BK=64 + pad 8
    __shared__ __align__(16) u16 Bs[64][72];

    int bid = blockIdx.x;
    int t = threadIdx.x;

    if (bid < ZS_BLKS) {
        // ---- zscan role: 4 adj rows per block
        int row0 = bid * ZROWS_PER_BLK;
        int* s = (int*)&As[0][0];           // 4 counters in (unused) LDS
        if (t < ZROWS_PER_BLK) s[t] = 0;
        __syncthreads();
        #pragma unroll
        for (int rr = 0; rr < ZROWS_PER_BLK; rr++) {
            int row = row0 + rr;
            int b = row / NTOK, i = row % NTOK;
            int f0 = (i / N_JOINTS) * N_JOINTS;
            const float* ar = adj + (size_t)b * NTOK * NTOK + (size_t)i * NTOK;
            int local = 0;
            for (int j4 = t * 4; j4 < NTOK; j4 += 1024) {
                float4 v4 = *(const float4*)(ar + j4);
                float vv[4] = {v4.x, v4.y, v4.z, v4.w};
                #pragma unroll
                for (int e = 0; e < 4; e++) {
                    int j = j4 + e;
                    if (j >= f0 && j < f0 + N_JOINTS) continue;
                    if (vv[e] == 0.0f) local++;
                }
            }
            if (local) atomicAdd(&s[rr], local);
        }
        __syncthreads();
        if (t < ZROWS_PER_BLK) cnt0[row0 + t] = s[t];
        return;
    }

    int gbid = bid - ZS_BLKS;
    int z = (gbid % 24) >> 3;
    int col_in = (gbid % 24 & 7) * 64;
    int r0 = (gbid / 24) * 128;
    const u16* WTz = WT + (size_t)z * D * D;
    const float* bias = (z == 0) ? bq : (z == 1) ? bk : bvb;
    u16* out = qkv + (size_t)z * ROWS * D;
    const bool act = (z == 2);

    int lane = t & 63, wid = t >> 6;
    int wr = (wid >> 1) * 64, wc = (wid & 1) * 32;
    int lr = lane & 15, lg = lane >> 4;

    f32x4 acc[4][2];
    f32x4 zz = (f32x4){0.f, 0.f, 0.f, 0.f};
    #pragma unroll
    for (int fi = 0; fi < 4; fi++) { acc[fi][0] = zz; acc[fi][1] = zz; }

    int rA = t >> 1, cA = (t & 1) * 32;
    int rB = t >> 2, cB = (t & 3) * 16;
    const u16* arow = Hb + (size_t)((r0 + rA < ROWS) ? (r0 + rA) : (ROWS - 1)) * D;
    const u16* brow = WTz + (size_t)(col_in + rB) * D;

    for (int k0 = 0; k0 < D; k0 += 64) {
        #pragma unroll
        for (int j = 0; j < 4; j++)
            *(short8_t*)&As[rA][cA + j * 8] = *(const short8_t*)(arow + k0 + cA + j * 8);
        #pragma unroll
        for (int j = 0; j < 2; j++)
            *(short8_t*)&Bs[rB][cB + j * 8] = *(const short8_t*)(brow + k0 + cB + j * 8);
        __syncthreads();
        #pragma unroll
        for (int kk = 0; kk < 2; kk++) {
            short8_t b0 = *(const short8_t*)&Bs[wc + lr][kk * 32 + lg * 8];
            short8_t b1 = *(const short8_t*)&Bs[wc + 16 + lr][kk * 32 + lg * 8];
            #pragma unroll
            for (int fi = 0; fi < 4; fi++) {
                short8_t a = *(const short8_t*)&As[wr + fi * 16 + lr][kk * 32 + lg * 8];
                acc[fi][0] = __builtin_amdgcn_mfma_f32_16x16x32_bf16(a, b0, acc[fi][0], 0, 0, 0);
                acc[fi][1] = __builtin_amdgcn_mfma_f32_16x16x32_bf16(a, b1, acc[fi][1], 0, 0, 0);
            }
        }
        __syncthreads();
    }

    #pragma unroll
    for (int fi = 0; fi < 4; fi++)
        #pragma unroll
        for (int fj = 0; fj < 2; fj++)
            #pragma unroll
            for (int j = 0; j < 4; j++) {
                int row = r0 + wr + fi * 16 + lg * 4 + j;
                int bcol = col_in + wc + fj * 16 + lr;
                if (row < ROWS) {
                    float v = acc[fi][fj][j] + bias[bcol];
                    if (act) v = fmaxf(v, 0.0f);
                    out[(size_t)row * D + bcol] = f2bf(v);
                }
            }
}

// ---- block-diagonal attention (bf16 q/k/v, padded LDS, register-blocked) --
__global__ __launch_bounds__(256)
void attn_kernel(const u16* __restrict__ q, const u16* __restrict__ k,
                 const u16* __restrict__ v, const float* __restrict__ adj,
                 const int* __restrict__ cnt0, u16* __restrict__ attnout,
                 float* __restrict__ m_buf, float* __restrict__ l_buf) {
    int bid = blockIdx.x;
    int b = bid / (NH * SEQ_LEN);
    int rem = bid % (NH * SEQ_LEN);
    int h = rem / SEQ_LEN, f = rem % SEQ_LEN;
    int fb = f * N_JOINTS;
    int base = b * NTOK + fb;

    __shared__ __align__(16) float Qs[25][68], Ks[25][68], Vs[25][68];
    __shared__ float sc[25][28], sl[25];

    int t = threadIdx.x;
    if (t < 200) {
        int i = t >> 3, d8 = (t & 7) * 8;
        size_t off = (size_t)(base + i) * D + h * DH + d8;
        short8_t qa = *(const short8_t*)(q + off);
        short8_t ka = *(const short8_t*)(k + off);
        short8_t va = *(const short8_t*)(v + off);
        #pragma unroll
        for (int e = 0; e < 8; e++) {
            Qs[i][d8 + e] = bf2f((u16)qa[e]);
            Ks[i][d8 + e] = bf2f((u16)ka[e]);
            Vs[i][d8 + e] = bf2f((u16)va[e]);
        }
    }
    __syncthreads();

    // score phase: 125 threads, each computes a 5-wide j-strip for one row i
    if (t < 125) {
        int i = t / 5, j0 = (t - i * 5) * 5;
        const float* adjr = adj + (size_t)b * NTOK * NTOK + (size_t)(fb + i) * NTOK + fb;
        float acc[5] = {0.f, 0.f, 0.f, 0.f, 0.f};
        for (int d0 = 0; d0 < 64; d0 += 4) {
            float4 qv = *(const float4*)&Qs[i][d0];
            #pragma unroll
            for (int jj = 0; jj < 5; jj++) {
                float4 kv = *(const float4*)&Ks[j0 + jj][d0];
                acc[jj] += qv.x * kv.x + qv.y * kv.y + qv.z * kv.z + qv.w * kv.w;
            }
        }
        #pragma unroll
        for (int jj = 0; jj < 5; jj++)
            sc[i][j0 + jj] = acc[jj] * 0.125f * adjr[j0 + jj];
    }
    __syncthreads();

    if (t < 25) {
        int i = t;
        float mx = sc[i][0];
        #pragma unroll
        for (int j = 1; j < 25; j++) mx = fmaxf(mx, sc[i][j]);
        int c0 = cnt0[base + i];
        if (c0 > 0) mx = fmaxf(mx, -0.0f);   // out-of-frame adj==0 -> logit -0.0
        float s = 0.0f;
        #pragma unroll
        for (int j = 0; j < 25; j++) { float p = expf(sc[i][j] - mx); sc[i][j] = p; s += p; }
        float l = s + (float)c0 * expf(-mx) + EPS_ATT;
        sl[i] = l;
        m_buf[(size_t)(b * NH + h) * NTOK + fb + i] = mx;
        l_buf[(size_t)(b * NH + h) * NTOK + fb + i] = l;
    }
    __syncthreads();

    // PV phase: 400 (i, d0-quad) chunks covered by 256 threads via loop
    for (int idx = t; idx < 400; idx += 256) {
        int i = idx >> 4, d0 = (idx & 15) << 2;
        float ax = 0.f, ay = 0.f, az = 0.f, aw = 0.f;
        #pragma unroll
        for (int j = 0; j < 25; j++) {
            float p = sc[i][j];
            float4 vv = *(const float4*)&Vs[j][d0];
            ax += p * vv.x; ay += p * vv.y; az += p * vv.z; aw += p * vv.w;
        }
        float sli = sl[i];
        short4_t o;
        o[0] = (short)f2bf(ax / sli);
        o[1] = (short)f2bf(ay / sli);
        o[2] = (short)f2bf(az / sli);
        o[3] = (short)f2bf(aw / sli);
        *(short4_t*)(attnout + (size_t)(base + i) * D + h * DH + d0) = o;
    }
}

// ---- fused fixup + out-proj + ReLU + LayerNorm -> f32 (BK=64) -------------
__global__ __launch_bounds__(512)
void proj_ln_kernel(u16* __restrict__ io, const u16* __restrict__ WT3,
                    const float* __restrict__ bo, const float* __restrict__ g,
                    const float* __restrict__ bb,
                    const float* __restrict__ adj, const int* __restrict__ cnt0,
                    const u16* __restrict__ v, const float* __restrict__ m_buf,
                    const float* __restrict__ l_buf, float* __restrict__ out) {
    __shared__ __align__(16) u16 As[64][72];   // BK=64 + pad 8
    __shared__ float rs[64], ss[64];
    __shared__ int frow[8], nfr, fj[32], nfj;

    int r0 = blockIdx.x * 64;
    int t = threadIdx.x;
    int lane = t & 63, w = t >> 6;
    int lr = lane & 15, lg = lane >> 4;

    // ---- fixup prologue (rare adj==0 rows, block-exclusive)
    if (t == 0) nfr = 0;
    __syncthreads();
    if (t < 64) {
        int grow = r0 + t;
        if (grow < ROWS && cnt0[grow] > 0) {
            int p = atomicAdd(&nfr, 1);
            if (p < 8) frow[p] = t;
        }
    }
    __syncthreads();
    int nf = nfr < 8 ? nfr : 8;
    for (int e = 0; e < nf; e++) {
        int grow = r0 + frow[e];
        int b = grow / NTOK, i = grow % NTOK;
        int f0 = (i / N_JOINTS) * N_JOINTS;
        const float* ar = adj + (size_t)b * NTOK * NTOK + (size_t)i * NTOK;
        if (t == 0) nfj = 0;
        __syncthreads();
        for (int j = t; j < NTOK; j += 512) {
            if (j >= f0 && j < f0 + N_JOINTS) continue;
            if (ar[j] == 0.0f) { int p = atomicAdd(&nfj, 1); if (p < 32) fj[p] = j; }
        }
        __syncthreads();
        int nj = nfj < 32 ? nfj : 32;
        int h = t >> 6;
        float mm = m_buf[(size_t)(b * NH + h) * NTOK + i];
        float ll = l_buf[(size_t)(b * NH + h) * NTOK + i];
        float wgt = expf(-mm) / ll;
        float add = 0.0f;
        for (int e2 = 0; e2 < nj; e2++)
            add += wgt * bf2f(v[(size_t)(b * NTOK + fj[e2]) * D + t]);
        size_t idx = (size_t)grow * D + t;
        io[idx] = f2bf(bf2f(io[idx]) + add);
        __syncthreads();
    }

    f32x4 acc[4][4];
    f32x4 zz = (f32x4){0.f, 0.f, 0.f, 0.f};
    #pragma unroll
    for (int a = 0; a < 4; a++)
        #pragma unroll
        for (int b2 = 0; b2 < 4; b2++) acc[a][b2] = zz;

    // staging: all 512 threads, each one short8 chunk (64 rows x 8 chunks)
    int rS = t >> 3, cS = (t & 7) * 8;
    int growS = r0 + rS;
    const u16* iorow = io + (size_t)((growS < ROWS) ? growS : (ROWS - 1)) * D;
    bool valS = growS < ROWS;

    for (int k0 = 0; k0 < 8; k0++) {
        short8_t vv = {0,0,0,0,0,0,0,0};
        if (valS) vv = *(const short8_t*)(iorow + k0 * 64 + cS);
        *(short8_t*)&As[rS][cS] = vv;
        __syncthreads();
        #pragma unroll
        for (int kk = 0; kk < 2; kk++) {
            short8_t b8[4];
            #pragma unroll
            for (int n2 = 0; n2 < 4; n2++)
                b8[n2] = *(const short8_t*)(WT3 + (size_t)(w * 64 + n2 * 16 + lr) * D +
                                            k0 * 64 + kk * 32 + lg * 8);
            #pragma unroll
            for (int m2 = 0; m2 < 4; m2++) {
                short8_t av = *(const short8_t*)&As[m2 * 16 + lr][kk * 32 + lg * 8];
                #pragma unroll
                for (int n2 = 0; n2 < 4; n2++)
                    acc[m2][n2] = __builtin_amdgcn_mfma_f32_16x16x32_bf16(av, b8[n2], acc[m2][n2], 0, 0, 0);
            }
        }
        __syncthreads();
    }

    float bias[4];
    #pragma unroll
    for (int n2 = 0; n2 < 4; n2++) bias[n2] = bo[w * 64 + n2 * 16 + lr];
    #pragma unroll
    for (int m2 = 0; m2 < 4; m2++)
        #pragma unroll
        for (int n2 = 0; n2 < 4; n2++)
            #pragma unroll
            for (int j = 0; j < 4; j++)
                acc[m2][n2][j] = fmaxf(acc[m2][n2][j] + bias[n2], 0.0f);

    if (t < 64) { rs[t] = 0.0f; ss[t] = 0.0f; }
    __syncthreads();
    #pragma unroll
    for (int m2 = 0; m2 < 4; m2++)
        #pragma unroll
        for (int j = 0; j < 4; j++) {
            float p = acc[m2][0][j] + acc[m2][1][j] + acc[m2][2][j] + acc[m2][3][j];
            p += __shfl_xor(p, 1); p += __shfl_xor(p, 2);
            p += __shfl_xor(p, 4); p += __shfl_xor(p, 8);
            if (lr == 0) atomicAdd(&rs[m2 * 16 + lg * 4 + j], p);
        }
    __syncthreads();
    #pragma unroll
    for (int m2 = 0; m2 < 4; m2++)
        #pragma unroll
        for (int j = 0; j < 4; j++) {
            float mean = rs[m2 * 16 + lg * 4 + j] * (1.0f / 512.0f);
            float qq = 0.0f;
            #pragma unroll
            for (int n2 = 0; n2 < 4; n2++) {
                float dd = acc[m2][n2][j] - mean;
                qq += dd * dd;
            }
            qq += __shfl_xor(qq, 1); qq += __shfl_xor(qq, 2);
            qq += __shfl_xor(qq, 4); qq += __shfl_xor(qq, 8);
            if (lr == 0) atomicAdd(&ss[m2 * 16 + lg * 4 + j], qq);
        }
    __syncthreads();
    float gv[4], bbv[4];
    #pragma unroll
    for (int n2 = 0; n2 < 4; n2++) {
        gv[n2]  = g[w * 64 + n2 * 16 + lr];
        bbv[n2] = bb[w * 64 + n2 * 16 + lr];
    }
    #pragma unroll
    for (int m2 = 0; m2 < 4; m2++)
        #pragma unroll
        for (int j = 0; j < 4; j++) {
            int row = m2 * 16 + lg * 4 + j;
            int grow = r0 + row;
            if (grow < ROWS) {
                float mean = rs[row] * (1.0f / 512.0f);
                float sd = sqrtf(ss[row] * (1.0f / 511.0f));   // ddof = 1
                float inv = 1.0f / (sd + EPS_LN);
                #pragma unroll
                for (int n2 = 0; n2 < 4; n2++)
                    out[(size_t)grow * D + w * 64 + n2 * 16 + lr] =
                        (acc[m2][n2][j] - mean) * inv * gv[n2] + bbv[n2];
            }
        }
}

// ---------------- launch --------------------------------------------------
extern "C" void kernel_launch(void* const* d_in, const int* in_sizes, int n_in,
                              void* d_out, int out_size, void* d_ws, size_t ws_size,
                              hipStream_t stream) {
    const int NX = NTOK * D * BS;        // 3072000
    const int NADJ = NTOK * NTOK * BS;   // 18000000
    const int NW = D * D;                // 262144
    float* outp = (float*)d_out;

    bool ok = (n_in == 12) && (in_sizes[0] == NX) && (in_sizes[1] == NADJ)
              && (in_sizes[2] == NW) && (in_sizes[3] == D)
              && (in_sizes[4] == NW) && (in_sizes[5] == D)
              && (in_sizes[6] == NW) && (in_sizes[7] == D)
              && (in_sizes[8] == NW) && (in_sizes[9] == D)
              && (in_sizes[10] == D) && (in_sizes[11] == D);
    if (!ok) {
        sentinel_kernel<<<(out_size + 255) / 256, 256, 0, stream>>>(outp, out_size, 50.0f);
        return;
    }
    if (ws_size < WS_NEEDED) {
        sentinel_kernel<<<(out_size + 255) / 256, 256, 0, stream>>>(outp, out_size, 100.0f);
        return;
    }
    const float* x   = (const float*)d_in[0];
    const float* adj = (const float*)d_in[1];
    const float* Wq  = (const float*)d_in[2];
    const float* bq  = (const float*)d_in[3];
    const float* Wk  = (const float*)d_in[4];
    const float* bk  = (const float*)d_in[5];
    const float* Wv  = (const float*)d_in[6];
    const float* bv  = (const float*)d_in[7];
    const float* Wo  = (const float*)d_in[8];
    const float* bo  = (const float*)d_in[9];
    const float* lng = (const float*)d_in[10];
    const float* lnb = (const float*)d_in[11];

    char* ws = (char*)d_ws;
    u16*   WT    = (u16*)(ws + OFF_WT);
    u16*   qkv   = (u16*)(ws + OFF_QKV);
    u16*   q     = qkv;
    u16*   k     = qkv + (size_t)ROWS * D;
    u16*   v     = qkv + (size_t)2 * ROWS * D;
    u16*   Hb    = (u16*)(ws + OFF_HATT);    // H (bf16), later attnout (bf16)
    float* m_buf = (float*)(ws + OFF_M);
    float* l_buf = (float*)(ws + OFF_L);
    int*   cnt0  = (int*)(ws + OFF_CNT);

    prep_kernel<<<2524, 256, 0, stream>>>(x, Wq, Wk, Wv, Wo, Hb, WT);
    gemm_qkv<<<ZS_BLKS + GEMM_BLKS, 256, 0, stream>>>(Hb, WT, bq, bk, bv, qkv, adj, cnt0);
    attn_kernel<<<BS * NH * SEQ_LEN, 256, 0, stream>>>(q, k, v, adj, cnt0, Hb,
                                                       m_buf, l_buf);
    proj_ln_kernel<<<(ROWS + 63) / 64, 512, 0, stream>>>(Hb, WT + (size_t)3 * D * D,
                                                         bo, lng, lnb,
                                                         adj, cnt0, v, m_buf, l_buf,
                                                         outp);
}

// Round 32
// 98.525 us; speedup vs baseline: 1.0755x; 1.0755x over previous
//
#include <hip/hip_runtime.h>
#include <stdint.h>

#define SEQ_LEN 120
#define N_JOINTS 25
#define NTOK 3000
#define D 512
#define NH 8
#define DH 64
#define BS 2
#define ROWS (BS*NTOK)       // 6000
#define EPS_ATT 1e-6f
#define EPS_LN 1e-6f

typedef unsigned short u16;
typedef __attribute__((ext_vector_type(8))) short short8_t;
typedef __attribute__((ext_vector_type(4))) short short4_t;
typedef __attribute__((ext_vector_type(4))) float f32x4;

// ws layout (bytes); ws_size = 288 MB confirmed
#define OFF_WT   ((size_t)65536)                      // 4*512*512*2 bf16
#define OFF_QKV  ((size_t)(OFF_WT + 2097152))         // 3*6000*512*2 bf16
#define OFF_HATT ((size_t)(OFF_QKV + 36864000))       // 6000*512*2 bf16 (H, then attnout)
#define OFF_M    ((size_t)(OFF_HATT + 6144000))       // 48000*4
#define OFF_L    ((size_t)(OFF_M + 192000))           // 48000*4
#define OFF_CNT  ((size_t)(OFF_L + 192000))           // 6000*4
#define WS_NEEDED (OFF_CNT + 24064)

#define GEMM_BLKS (24*47)    // 1128 gemm tiles, then zscan tail
#define ZROWS_PER_BLK 4      // zscan rows per tail block
#define ZS_BLKS (ROWS / ZROWS_PER_BLK)   // 1500

__device__ inline u16 f2bf(float f) {
    union { float f; uint32_t u; } c; c.f = f;
    uint32_t u = c.u;
    u += 0x7FFFu + ((u >> 16) & 1u);   // RNE
    return (u16)(u >> 16);
}
__device__ inline float bf2f(u16 h) {
    union { uint32_t u; float f; } c; c.u = ((uint32_t)h) << 16;
    return c.f;
}

__global__ void sentinel_kernel(float* __restrict__ out, int n, float v) {
    int i = blockIdx.x * 256 + threadIdx.x;
    if (i < n) out[i] = v;
}

// ---- prep: addpe [0,1500) | transW [1500,2524) ----------------------------
__global__ __launch_bounds__(256)
void prep_kernel(const float* __restrict__ x,
                 const float* __restrict__ Wq, const float* __restrict__ Wk,
                 const float* __restrict__ Wv, const float* __restrict__ Wo,
                 u16* __restrict__ Hb, u16* __restrict__ WT) {
    int bid = blockIdx.x;
    int t = threadIdx.x;
    __shared__ float tile[32][33];

    if (bid < 1500) {
        // ---- addpe: Hb = bf16(x + pe), PE computed inline
        int idx = (bid * 256 + t) * 8;
        int r = idx >> 9, c = idx & 511;
        int p = (r % NTOK) % N_JOINTS;
        const float* xr = x + idx;
        short8_t o;
        #pragma unroll
        for (int e = 0; e < 8; e++) {
            int cc = c + e;
            float dt = expf((float)(cc & ~1) * (-9.210340371976184f / 512.0f));
            float arg = (float)p * dt;
            float pev = (cc & 1) ? cosf(arg) : sinf(arg);
            o[e] = (short)f2bf(xr[e] + pev);
        }
        *(short8_t*)(Hb + idx) = o;
    } else {
        // ---- transW: WT[w][n][k] = bf16(W[w][k][n])
        int idx2 = bid - 1500;              // 0..1023
        int w = idx2 >> 8;
        int rem = idx2 & 255;
        int n0 = (rem & 15) * 32;
        int k0 = (rem >> 4) * 32;
        const float* W = (w == 0) ? Wq : (w == 1) ? Wk : (w == 2) ? Wv : Wo;
        int tx = t & 31, ty2 = t >> 5;      // ty2 0..7
        #pragma unroll
        for (int e = 0; e < 4; e++) {
            int row = ty2 + e * 8;
            tile[row][tx] = W[(size_t)(k0 + row) * D + n0 + tx];
        }
        __syncthreads();
        #pragma unroll
        for (int e = 0; e < 4; e++) {
            int row = ty2 + e * 8;
            WT[(size_t)w * D * D + (size_t)(n0 + row) * D + k0 + tx] = f2bf(tile[tx][row]);
        }
    }
}

// ---- fused QKV GEMM (BM=128, BK=64) + zscan tail (4 rows/block) -----------
__global__ __launch_bounds__(256)
void gemm_qkv(const u16* __restrict__ Hb, const u16* __restrict__ WT,
              const float* __restrict__ bq, const float* __restrict__ bk,
              const float* __restrict__ bvb, u16* __restrict__ qkv,
              const float* __restrict__ adj, int* __restrict__ cnt0) {
    __shared__ __align__(16) u16 As[128][72];   // BK=64 + pad 8
    __shared__ __align__(16) u16 Bs[64][72];

    int bid = blockIdx.x;
    int t = threadIdx.x;

    if (bid >= GEMM_BLKS) {
        // ---- zscan role: 4 adj rows per block, high-ILP streaming
        int row0 = (bid - GEMM_BLKS) * ZROWS_PER_BLK;
        int* s = (int*)&As[0][0];           // 4 counters in (unused) LDS
        if (t < ZROWS_PER_BLK) s[t] = 0;
        __syncthreads();
        #pragma unroll
        for (int rr = 0; rr < ZROWS_PER_BLK; rr++) {
            int row = row0 + rr;
            int b = row / NTOK, i = row % NTOK;
            int f0 = (i / N_JOINTS) * N_JOINTS;
            const float* ar = adj + (size_t)b * NTOK * NTOK + (size_t)i * NTOK;
            int local = 0;
            for (int j4 = t * 4; j4 < NTOK; j4 += 1024) {
                float4 v4 = *(const float4*)(ar + j4);
                float vv[4] = {v4.x, v4.y, v4.z, v4.w};
                #pragma unroll
                for (int e = 0; e < 4; e++) {
                    int j = j4 + e;
                    if (j >= f0 && j < f0 + N_JOINTS) continue;
                    if (vv[e] == 0.0f) local++;
                }
            }
            if (local) atomicAdd(&s[rr], local);
        }
        __syncthreads();
        if (t < ZROWS_PER_BLK) cnt0[row0 + t] = s[t];
        return;
    }

    int z = (bid % 24) >> 3;
    int col_in = (bid % 24 & 7) * 64;
    int r0 = (bid / 24) * 128;
    const u16* WTz = WT + (size_t)z * D * D;
    const float* bias = (z == 0) ? bq : (z == 1) ? bk : bvb;
    u16* out = qkv + (size_t)z * ROWS * D;
    const bool act = (z == 2);

    int lane = t & 63, wid = t >> 6;
    int wr = (wid >> 1) * 64, wc = (wid & 1) * 32;
    int lr = lane & 15, lg = lane >> 4;

    f32x4 acc[4][2];
    f32x4 zz = (f32x4){0.f, 0.f, 0.f, 0.f};
    #pragma unroll
    for (int fi = 0; fi < 4; fi++) { acc[fi][0] = zz; acc[fi][1] = zz; }

    int rA = t >> 1, cA = (t & 1) * 32;
    int rB = t >> 2, cB = (t & 3) * 16;
    const u16* arow = Hb + (size_t)((r0 + rA < ROWS) ? (r0 + rA) : (ROWS - 1)) * D;
    const u16* brow = WTz + (size_t)(col_in + rB) * D;

    for (int k0 = 0; k0 < D; k0 += 64) {
        #pragma unroll
        for (int j = 0; j < 4; j++)
            *(short8_t*)&As[rA][cA + j * 8] = *(const short8_t*)(arow + k0 + cA + j * 8);
        #pragma unroll
        for (int j = 0; j < 2; j++)
            *(short8_t*)&Bs[rB][cB + j * 8] = *(const short8_t*)(brow + k0 + cB + j * 8);
        __syncthreads();
        #pragma unroll
        for (int kk = 0; kk < 2; kk++) {
            short8_t b0 = *(const short8_t*)&Bs[wc + lr][kk * 32 + lg * 8];
            short8_t b1 = *(const short8_t*)&Bs[wc + 16 + lr][kk * 32 + lg * 8];
            #pragma unroll
            for (int fi = 0; fi < 4; fi++) {
                short8_t a = *(const short8_t*)&As[wr + fi * 16 + lr][kk * 32 + lg * 8];
                acc[fi][0] = __builtin_amdgcn_mfma_f32_16x16x32_bf16(a, b0, acc[fi][0], 0, 0, 0);
                acc[fi][1] = __builtin_amdgcn_mfma_f32_16x16x32_bf16(a, b1, acc[fi][1], 0, 0, 0);
            }
        }
        __syncthreads();
    }

    #pragma unroll
    for (int fi = 0; fi < 4; fi++)
        #pragma unroll
        for (int fj = 0; fj < 2; fj++)
            #pragma unroll
            for (int j = 0; j < 4; j++) {
                int row = r0 + wr + fi * 16 + lg * 4 + j;
                int bcol = col_in + wc + fj * 16 + lr;
                if (row < ROWS) {
                    float v = acc[fi][fj][j] + bias[bcol];
                    if (act) v = fmaxf(v, 0.0f);
                    out[(size_t)row * D + bcol] = f2bf(v);
                }
            }
}

// ---- block-diagonal attention (bf16 q/k/v, padded LDS, register-blocked) --
__global__ __launch_bounds__(256)
void attn_kernel(const u16* __restrict__ q, const u16* __restrict__ k,
                 const u16* __restrict__ v, const float* __restrict__ adj,
                 const int* __restrict__ cnt0, u16* __restrict__ attnout,
                 float* __restrict__ m_buf, float* __restrict__ l_buf) {
    int bid = blockIdx.x;
    int b = bid / (NH * SEQ_LEN);
    int rem = bid % (NH * SEQ_LEN);
    int h = rem / SEQ_LEN, f = rem % SEQ_LEN;
    int fb = f * N_JOINTS;
    int base = b * NTOK + fb;

    __shared__ __align__(16) float Qs[25][68], Ks[25][68], Vs[25][68];
    __shared__ float sc[25][28], sl[25];

    int t = threadIdx.x;
    if (t < 200) {
        int i = t >> 3, d8 = (t & 7) * 8;
        size_t off = (size_t)(base + i) * D + h * DH + d8;
        short8_t qa = *(const short8_t*)(q + off);
        short8_t ka = *(const short8_t*)(k + off);
        short8_t va = *(const short8_t*)(v + off);
        #pragma unroll
        for (int e = 0; e < 8; e++) {
            Qs[i][d8 + e] = bf2f((u16)qa[e]);
            Ks[i][d8 + e] = bf2f((u16)ka[e]);
            Vs[i][d8 + e] = bf2f((u16)va[e]);
        }
    }
    __syncthreads();

    // score phase: 125 threads, each computes a 5-wide j-strip for one row i
    if (t < 125) {
        int i = t / 5, j0 = (t - i * 5) * 5;
        const float* adjr = adj + (size_t)b * NTOK * NTOK + (size_t)(fb + i) * NTOK + fb;
        float acc[5] = {0.f, 0.f, 0.f, 0.f, 0.f};
        for (int d0 = 0; d0 < 64; d0 += 4) {
            float4 qv = *(const float4*)&Qs[i][d0];
            #pragma unroll
            for (int jj = 0; jj < 5; jj++) {
                float4 kv = *(const float4*)&Ks[j0 + jj][d0];
                acc[jj] += qv.x * kv.x + qv.y * kv.y + qv.z * kv.z + qv.w * kv.w;
            }
        }
        #pragma unroll
        for (int jj = 0; jj < 5; jj++)
            sc[i][j0 + jj] = acc[jj] * 0.125f * adjr[j0 + jj];
    }
    __syncthreads();

    if (t < 25) {
        int i = t;
        float mx = sc[i][0];
        #pragma unroll
        for (int j = 1; j < 25; j++) mx = fmaxf(mx, sc[i][j]);
        int c0 = cnt0[base + i];
        if (c0 > 0) mx = fmaxf(mx, -0.0f);   // out-of-frame adj==0 -> logit -0.0
        float s = 0.0f;
        #pragma unroll
        for (int j = 0; j < 25; j++) { float p = expf(sc[i][j] - mx); sc[i][j] = p; s += p; }
        float l = s + (float)c0 * expf(-mx) + EPS_ATT;
        sl[i] = l;
        m_buf[(size_t)(b * NH + h) * NTOK + fb + i] = mx;
        l_buf[(size_t)(b * NH + h) * NTOK + fb + i] = l;
    }
    __syncthreads();

    // PV phase: 400 (i, d0-quad) chunks covered by 256 threads via loop
    for (int idx = t; idx < 400; idx += 256) {
        int i = idx >> 4, d0 = (idx & 15) << 2;
        float ax = 0.f, ay = 0.f, az = 0.f, aw = 0.f;
        #pragma unroll
        for (int j = 0; j < 25; j++) {
            float p = sc[i][j];
            float4 vv = *(const float4*)&Vs[j][d0];
            ax += p * vv.x; ay += p * vv.y; az += p * vv.z; aw += p * vv.w;
        }
        float sli = sl[i];
        short4_t o;
        o[0] = (short)f2bf(ax / sli);
        o[1] = (short)f2bf(ay / sli);
        o[2] = (short)f2bf(az / sli);
        o[3] = (short)f2bf(aw / sli);
        *(short4_t*)(attnout + (size_t)(base + i) * D + h * DH + d0) = o;
    }
}

// ---- fused fixup + out-proj + ReLU + LayerNorm -> f32 (BK=64) -------------
__global__ __launch_bounds__(512)
void proj_ln_kernel(u16* __restrict__ io, const u16* __restrict__ WT3,
                    const float* __restrict__ bo, const float* __restrict__ g,
                    const float* __restrict__ bb,
                    const float* __restrict__ adj, const int* __restrict__ cnt0,
                    const u16* __restrict__ v, const float* __restrict__ m_buf,
                    const float* __restrict__ l_buf, float* __restrict__ out) {
    __shared__ __align__(16) u16 As[64][72];   // BK=64 + pad 8
    __shared__ float rs[64], ss[64];
    __shared__ int frow[8], nfr, fj[32], nfj;

    int r0 = blockIdx.x * 64;
    int t = threadIdx.x;
    int lane = t & 63, w = t >> 6;
    int lr = lane & 15, lg = lane >> 4;

    // ---- fixup prologue (rare adj==0 rows, block-exclusive)
    if (t == 0) nfr = 0;
    __syncthreads();
    if (t < 64) {
        int grow = r0 + t;
        if (grow < ROWS && cnt0[grow] > 0) {
            int p = atomicAdd(&nfr, 1);
            if (p < 8) frow[p] = t;
        }
    }
    __syncthreads();
    int nf = nfr < 8 ? nfr : 8;
    for (int e = 0; e < nf; e++) {
        int grow = r0 + frow[e];
        int b = grow / NTOK, i = grow % NTOK;
        int f0 = (i / N_JOINTS) * N_JOINTS;
        const float* ar = adj + (size_t)b * NTOK * NTOK + (size_t)i * NTOK;
        if (t == 0) nfj = 0;
        __syncthreads();
        for (int j = t; j < NTOK; j += 512) {
            if (j >= f0 && j < f0 + N_JOINTS) continue;
            if (ar[j] == 0.0f) { int p = atomicAdd(&nfj, 1); if (p < 32) fj[p] = j; }
        }
        __syncthreads();
        int nj = nfj < 32 ? nfj : 32;
        int h = t >> 6;
        float mm = m_buf[(size_t)(b * NH + h) * NTOK + i];
        float ll = l_buf[(size_t)(b * NH + h) * NTOK + i];
        float wgt = expf(-mm) / ll;
        float add = 0.0f;
        for (int e2 = 0; e2 < nj; e2++)
            add += wgt * bf2f(v[(size_t)(b * NTOK + fj[e2]) * D + t]);
        size_t idx = (size_t)grow * D + t;
        io[idx] = f2bf(bf2f(io[idx]) + add);
        __syncthreads();
    }

    f32x4 acc[4][4];
    f32x4 zz = (f32x4){0.f, 0.f, 0.f, 0.f};
    #pragma unroll
    for (int a = 0; a < 4; a++)
        #pragma unroll
        for (int b2 = 0; b2 < 4; b2++) acc[a][b2] = zz;

    // staging: all 512 threads, each one short8 chunk (64 rows x 8 chunks)
    int rS = t >> 3, cS = (t & 7) * 8;
    int growS = r0 + rS;
    const u16* iorow = io + (size_t)((growS < ROWS) ? growS : (ROWS - 1)) * D;
    bool valS = growS < ROWS;

    for (int k0 = 0; k0 < 8; k0++) {
        short8_t vv = {0,0,0,0,0,0,0,0};
        if (valS) vv = *(const short8_t*)(iorow + k0 * 64 + cS);
        *(short8_t*)&As[rS][cS] = vv;
        __syncthreads();
        #pragma unroll
        for (int kk = 0; kk < 2; kk++) {
            short8_t b8[4];
            #pragma unroll
            for (int n2 = 0; n2 < 4; n2++)
                b8[n2] = *(const short8_t*)(WT3 + (size_t)(w * 64 + n2 * 16 + lr) * D +
                                            k0 * 64 + kk * 32 + lg * 8);
            #pragma unroll
            for (int m2 = 0; m2 < 4; m2++) {
                short8_t av = *(const short8_t*)&As[m2 * 16 + lr][kk * 32 + lg * 8];
                #pragma unroll
                for (int n2 = 0; n2 < 4; n2++)
                    acc[m2][n2] = __builtin_amdgcn_mfma_f32_16x16x32_bf16(av, b8[n2], acc[m2][n2], 0, 0, 0);
            }
        }
        __syncthreads();
    }

    float bias[4];
    #pragma unroll
    for (int n2 = 0; n2 < 4; n2++) bias[n2] = bo[w * 64 + n2 * 16 + lr];
    #pragma unroll
    for (int m2 = 0; m2 < 4; m2++)
        #pragma unroll
        for (int n2 = 0; n2 < 4; n2++)
            #pragma unroll
            for (int j = 0; j < 4; j++)
                acc[m2][n2][j] = fmaxf(acc[m2][n2][j] + bias[n2], 0.0f);

    if (t < 64) { rs[t] = 0.0f; ss[t] = 0.0f; }
    __syncthreads();
    #pragma unroll
    for (int m2 = 0; m2 < 4; m2++)
        #pragma unroll
        for (int j = 0; j < 4; j++) {
            float p = acc[m2][0][j] + acc[m2][1][j] + acc[m2][2][j] + acc[m2][3][j];
            p += __shfl_xor(p, 1); p += __shfl_xor(p, 2);
            p += __shfl_xor(p, 4); p += __shfl_xor(p, 8);
            if (lr == 0) atomicAdd(&rs[m2 * 16 + lg * 4 + j], p);
        }
    __syncthreads();
    #pragma unroll
    for (int m2 = 0; m2 < 4; m2++)
        #pragma unroll
        for (int j = 0; j < 4; j++) {
            float mean = rs[m2 * 16 + lg * 4 + j] * (1.0f / 512.0f);
            float qq = 0.0f;
            #pragma unroll
            for (int n2 = 0; n2 < 4; n2++) {
                float dd = acc[m2][n2][j] - mean;
                qq += dd * dd;
            }
            qq += __shfl_xor(qq, 1); qq += __shfl_xor(qq, 2);
            qq += __shfl_xor(qq, 4); qq += __shfl_xor(qq, 8);
            if (lr == 0) atomicAdd(&ss[m2 * 16 + lg * 4 + j], qq);
        }
    __syncthreads();
    float gv[4], bbv[4];
    #pragma unroll
    for (int n2 = 0; n2 < 4; n2++) {
        gv[n2]  = g[w * 64 + n2 * 16 + lr];
        bbv[n2] = bb[w * 64 + n2 * 16 + lr];
    }
    #pragma unroll
    for (int m2 = 0; m2 < 4; m2++)
        #pragma unroll
        for (int j = 0; j < 4; j++) {
            int row = m2 * 16 + lg * 4 + j;
            int grow = r0 + row;
            if (grow < ROWS) {
                float mean = rs[row] * (1.0f / 512.0f);
                float sd = sqrtf(ss[row] * (1.0f / 511.0f));   // ddof = 1
                float inv = 1.0f / (sd + EPS_LN);
                #pragma unroll
                for (int n2 = 0; n2 < 4; n2++)
                    out[(size_t)grow * D + w * 64 + n2 * 16 + lr] =
                        (acc[m2][n2][j] - mean) * inv * gv[n2] + bbv[n2];
            }
        }
}

// ---------------- launch --------------------------------------------------
extern "C" void kernel_launch(void* const* d_in, const int* in_sizes, int n_in,
                              void* d_out, int out_size, void* d_ws, size_t ws_size,
                              hipStream_t stream) {
    const int NX = NTOK * D * BS;        // 3072000
    const int NADJ = NTOK * NTOK * BS;   // 18000000
    const int NW = D * D;                // 262144
    float* outp = (float*)d_out;

    bool ok = (n_in == 12) && (in_sizes[0] == NX) && (in_sizes[1] == NADJ)
              && (in_sizes[2] == NW) && (in_sizes[3] == D)
              && (in_sizes[4] == NW) && (in_sizes[5] == D)
              && (in_sizes[6] == NW) && (in_sizes[7] == D)
              && (in_sizes[8] == NW) && (in_sizes[9] == D)
              && (in_sizes[10] == D) && (in_sizes[11] == D);
    if (!ok) {
        sentinel_kernel<<<(out_size + 255) / 256, 256, 0, stream>>>(outp, out_size, 50.0f);
        return;
    }
    if (ws_size < WS_NEEDED) {
        sentinel_kernel<<<(out_size + 255) / 256, 256, 0, stream>>>(outp, out_size, 100.0f);
        return;
    }
    const float* x   = (const float*)d_in[0];
    const float* adj = (const float*)d_in[1];
    const float* Wq  = (const float*)d_in[2];
    const float* bq  = (const float*)d_in[3];
    const float* Wk  = (const float*)d_in[4];
    const float* bk  = (const float*)d_in[5];
    const float* Wv  = (const float*)d_in[6];
    const float* bv  = (const float*)d_in[7];
    const float* Wo  = (const float*)d_in[8];
    const float* bo  = (const float*)d_in[9];
    const float* lng = (const float*)d_in[10];
    const float* lnb = (const float*)d_in[11];

    char* ws = (char*)d_ws;
    u16*   WT    = (u16*)(ws + OFF_WT);
    u16*   qkv   = (u16*)(ws + OFF_QKV);
    u16*   q     = qkv;
    u16*   k     = qkv + (size_t)ROWS * D;
    u16*   v     = qkv + (size_t)2 * ROWS * D;
    u16*   Hb    = (u16*)(ws + OFF_HATT);    // H (bf16), later attnout (bf16)
    float* m_buf = (float*)(ws + OFF_M);
    float* l_buf = (float*)(ws + OFF_L);
    int*   cnt0  = (int*)(ws + OFF_CNT);

    prep_kernel<<<2524, 256, 0, stream>>>(x, Wq, Wk, Wv, Wo, Hb, WT);
    gemm_qkv<<<GEMM_BLKS + ZS_BLKS, 256, 0, stream>>>(Hb, WT, bq, bk, bv, qkv, adj, cnt0);
    attn_kernel<<<BS * NH * SEQ_LEN, 256, 0, stream>>>(q, k, v, adj, cnt0, Hb,
                                                       m_buf, l_buf);
    proj_ln_kernel<<<(ROWS + 63) / 64, 512, 0, stream>>>(Hb, WT + (size_t)3 * D * D,
                                                         bo, lng, lnb,
                                                         adj, cnt0, v, m_buf, l_buf,
                                                         outp);
}